// Round 22
// baseline (337.012 us; speedup 1.0000x reference)
//
#include <hip/hip_runtime.h>
#include <hip/hip_bf16.h>

// B=2,S=2048 -> T=4096 tokens, D=1024, H=2048, E=8, top_k=2
#define TOK 4096
#define DD 1024
#define HH 2048
#define NE 8
#define RTOT (TOK * 2)
#define MAXT1 72
#define HALFSLOTS 68   // worst-case M-tiles in a 4-expert half: 64 full + 4 partial

typedef __attribute__((ext_vector_type(8))) short bf16x8;
typedef __attribute__((ext_vector_type(4))) float f32x4;

static __device__ __forceinline__ unsigned short f2bf(float f) {
  union { float f; unsigned int u; } v; v.f = f;
  unsigned int r = v.u + 0x7fffu + ((v.u >> 16) & 1u);
  return (unsigned short)(r >> 16);
}

// async global->LDS, 16B/lane; LDS dest = wave-uniform base + lane*16
static __device__ __forceinline__ void gload16(const unsigned short* g, unsigned short* l) {
  __builtin_amdgcn_global_load_lds(
      (const __attribute__((address_space(1))) unsigned int*)g,
      (__attribute__((address_space(3))) unsigned int*)l, 16, 0, 0);
}

// packed f32x2 -> bf16x2 (RNE), single HW instruction
#define CVT(d, lo, hi) asm("v_cvt_pk_bf16_f32 %0, %1, %2" : "=v"(d) : "v"(lo), "v"(hi))

#define BARX() do { asm volatile("" ::: "memory"); __builtin_amdgcn_s_barrier(); asm volatile("" ::: "memory"); } while (0)
#define VMCNT8() asm volatile("s_waitcnt vmcnt(8)" ::: "memory")
#define VMCNT0() asm volatile("s_waitcnt vmcnt(0)" ::: "memory")

// ---- shared 64x64 transpose-tile helpers (proven R11/R21 code path) ----
// phase 1 into tbuf[64][72]; phase 2 writes 16B rows.
#define TTILE_LOAD(IN, C)                                                 \
  do {                                                                    \
    _Pragma("unroll")                                                     \
    for (int p = 0; p < 4; ++p) {                                         \
      const int rb = (wv * 4 + p) * 4;                                    \
      ushort4 o;                                                          \
      o.x = f2bf((IN)[(size_t)(r0 + rb + 0) * (C) + c0 + lane]);          \
      o.y = f2bf((IN)[(size_t)(r0 + rb + 1) * (C) + c0 + lane]);          \
      o.z = f2bf((IN)[(size_t)(r0 + rb + 2) * (C) + c0 + lane]);          \
      o.w = f2bf((IN)[(size_t)(r0 + rb + 3) * (C) + c0 + lane]);          \
      *(ushort4*)&tbuf[lane * 72 + rb] = o;                               \
    }                                                                     \
  } while (0)

// ---------------- pre-kernel: router + wgu transpose for experts 0-3 ----------------
// period 5: rem==0 -> router (1024), else transpose (4096).
__global__ __launch_bounds__(256) void pre_k(
    const float* __restrict__ x, const float* __restrict__ gw,
    unsigned short* __restrict__ xb, int* __restrict__ topi, float* __restrict__ topp,
    int* __restrict__ counts, int* __restrict__ chunkcnt,
    const float* __restrict__ w1, const float* __restrict__ w2,
    unsigned short* __restrict__ wgu) {
  __shared__ unsigned short tbuf[64 * 72];
  const int tid = threadIdx.x;
  const int lane = tid & 63, wv = tid >> 6;
  const int rb5 = blockIdx.x / 5;

  if (blockIdx.x - rb5 * 5 == 0) {
    // ---- router ----
    const int t = rb5 * 4 + wv;
    const float4* xr = (const float4*)(x + (size_t)t * DD);
    unsigned int* xw = (unsigned int*)(xb + (size_t)t * DD);
    float acc[NE];
#pragma unroll
    for (int e = 0; e < NE; ++e) acc[e] = 0.f;
#pragma unroll
    for (int i = 0; i < 4; ++i) {
      const float4 xv = xr[i * 64 + lane];
      unsigned int p0, p1;
      CVT(p0, xv.x, xv.y);
      CVT(p1, xv.z, xv.w);
      xw[(i * 64 + lane) * 2] = p0;
      xw[(i * 64 + lane) * 2 + 1] = p1;
#pragma unroll
      for (int e = 0; e < NE; ++e) {
        const float4 gv = ((const float4*)(gw + (size_t)e * DD))[i * 64 + lane];
        acc[e] += xv.x * gv.x + xv.y * gv.y + xv.z * gv.z + xv.w * gv.w;
      }
    }
#pragma unroll
    for (int e = 0; e < NE; ++e)
#pragma unroll
      for (int s = 32; s > 0; s >>= 1) acc[e] += __shfl_xor(acc[e], s, 64);
    if (lane == 0) {
      int i0 = 0; float v0 = acc[0];
#pragma unroll
      for (int e = 1; e < NE; ++e) if (acc[e] > v0) { v0 = acc[e]; i0 = e; }
      int i1 = -1; float v1 = -1e30f;
#pragma unroll
      for (int e = 0; e < NE; ++e) if (e != i0 && acc[e] > v1) { v1 = acc[e]; i1 = e; }
      const float ex = __expf(v1 - v0);
      const float inv = 1.f / (1.f + ex);
      topi[t * 2] = i0; topi[t * 2 + 1] = i1;
      topp[t * 2] = inv; topp[t * 2 + 1] = ex * inv;
      atomicAdd(&counts[i0], 1); atomicAdd(&counts[i1], 1);
      const int c = t >> 8;
      atomicAdd(&chunkcnt[i0 * 16 + c], 1);
      atomicAdd(&chunkcnt[i1 * 16 + c], 1);
    }
    return;
  }

  // ---- wgu transpose, experts 0-3: idx 0..4095 ----
  const int idx = blockIdx.x - rb5 - 1;
  const int zz = idx >> 9;                 // 0..7
  const int mat = zz >> 2, e = zz & 3;
  const int xt = idx & 511;
  const float* in = (mat ? w2 : w1) + (size_t)e * DD * HH;
  const int tc = xt & 31, tr = xt >> 5;
  const int c0 = tc * 64, r0 = tr * 64;
  TTILE_LOAD(in, HH);
  __syncthreads();
#pragma unroll
  for (int q = 0; q < 2; ++q) {
    const int i2 = q * 256 + tid;
    const int crow = i2 >> 3, seg = i2 & 7;
    const int j = c0 + crow;
    const int R = ((j >> 4) << 5) + (j & 15) + mat * 16;
    *(uint4*)&wgu[((size_t)e * 2 * HH + R) * DD + r0 + seg * 8] =
        *(const uint4*)&tbuf[crow * 72 + seg * 8];
  }
}

// ---------------- parallel compact: 128 blocks = (e, 256-token chunk) ----------------
__global__ __launch_bounds__(256) void compact_k(
    const int* __restrict__ topi, const float* __restrict__ topp,
    const int* __restrict__ counts, const int* __restrict__ chunkcnt,
    int* __restrict__ perm, float* __restrict__ prow) {
  const int e = blockIdx.x >> 4, c = blockIdx.x & 15;
  const int tid = threadIdx.x, lane = tid & 63, wv = tid >> 6;
  __shared__ int wsum[4];
  __shared__ int base_s;
  if (tid == 0) {
    int b = 0;
    for (int i = 0; i < e; ++i) b += counts[i];
    for (int i = 0; i < c; ++i) b += chunkcnt[e * 16 + i];
    base_s = b;
  }
  const int t = c * 256 + tid;
  const int a = topi[2 * t], bq = topi[2 * t + 1];
  const int k = (a == e) ? 0 : ((bq == e) ? 1 : -1);
  const unsigned long long bal = __ballot(k >= 0);
  const int rank = __popcll(bal & ((1ull << lane) - 1ull));
  if (lane == 0) wsum[wv] = __popcll(bal);
  __syncthreads();
  int woff = 0;
#pragma unroll
  for (int i = 0; i < 4; ++i) if (i < wv) woff += wsum[i];
  if (k >= 0) {
    const int pos = base_s + woff + rank;
    perm[pos] = t;
    prow[pos] = topp[2 * t + k];
  }
}

// ---- tile decode over expert range [elo, elo+4): tix -> (e,m0,off,ne) ----
static __device__ __forceinline__ bool decodeHalf(const int* counts, int tix, int elo,
                                                  int& e, int& m0, int& off, int& ne) {
  off = 0;
  for (int i = 0; i < elo; ++i) off += counts[i];
  int t = tix;
  for (e = elo; e < elo + 4; ++e) {
    const int c = counts[e];
    const int nt = (c + 127) >> 7;
    if (t < nt) { m0 = t << 7; ne = c; return true; }
    t -= nt; off += c;
  }
  return false;
}

// ---------------- GEMM1 half-dispatch with interleaved transpose blocks ----------------
// period 3: rem==0 -> gemm tile for experts [elo,elo+4); else transpose block:
//   tmode 0: wgu transpose for experts 4-7 (runs in gemm1a, consumed by gemm1b)
//   tmode 1: w3t transpose all experts (runs in gemm1b, consumed by gemm2)
__global__ __launch_bounds__(256) void gemm1_k(
    const unsigned short* __restrict__ Xb, const unsigned short* __restrict__ wgu,
    const int* __restrict__ counts, const int* __restrict__ perm,
    unsigned short* __restrict__ hbuf,
    const float* __restrict__ w1, const float* __restrict__ w2,
    const float* __restrict__ w3, unsigned short* __restrict__ wguo,
    unsigned short* __restrict__ w3t, int elo, int tmode) {
  __shared__ unsigned short As[2][128 * 64];
  __shared__ unsigned short Bs[2][128 * 64];

  const int tid = threadIdx.x, lane = tid & 63, wv = tid >> 6;
  const int grp = blockIdx.x / 3, rem = blockIdx.x % 3;

  if (rem) {
    const int idx = grp * 2 + (rem - 1);
    if (idx >= 4096) return;
    unsigned short* tbuf = &As[0][0];
    if (tmode == 0) {
      // wgu transpose, experts 4-7
      const int zz = idx >> 9;
      const int mat = zz >> 2, e = (zz & 3) + 4;
      const int xt = idx & 511;
      const float* in = (mat ? w2 : w1) + (size_t)e * DD * HH;
      const int tc = xt & 31, tr = xt >> 5;
      const int c0 = tc * 64, r0 = tr * 64;
      TTILE_LOAD(in, HH);
      __syncthreads();
#pragma unroll
      for (int q = 0; q < 2; ++q) {
        const int i2 = q * 256 + tid;
        const int crow = i2 >> 3, seg = i2 & 7;
        const int j = c0 + crow;
        const int R = ((j >> 4) << 5) + (j & 15) + mat * 16;
        *(uint4*)&wguo[((size_t)e * 2 * HH + R) * DD + r0 + seg * 8] =
            *(const uint4*)&tbuf[crow * 72 + seg * 8];
      }
    } else {
      // w3t transpose, all experts
      const int e = idx >> 9, xt = idx & 511;
      const int tc = xt & 15, tr = xt >> 4;
      const int c0 = tc * 64, r0 = tr * 64;
      const float* in = w3 + (size_t)e * HH * DD;
      TTILE_LOAD(in, DD);
      __syncthreads();
#pragma unroll
      for (int q = 0; q < 2; ++q) {
        const int i2 = q * 256 + tid;
        const int crow = i2 >> 3, seg = i2 & 7;
        *(uint4*)&w3t[((size_t)e * DD + c0 + crow) * HH + r0 + seg * 8] =
            *(const uint4*)&tbuf[crow * 72 + seg * 8];
      }
    }
    return;
  }

  const int g = grp;
  const int bx = g & 31;
  int e, m0, off, ne;
  if (!decodeHalf(counts, g >> 5, elo, e, m0, off, ne)) return;

  const int srow = lane >> 3;
  const int schunk = ((lane & 7) ^ srow) * 8;

  const unsigned short* pA[4];
  const unsigned short* pB[4];
#pragma unroll
  for (int q = 0; q < 4; ++q) {
    const int row = wv * 32 + q * 8 + srow;
    pA[q] = Xb + (size_t)perm[off + min(m0 + row, ne - 1)] * DD + schunk;
    pB[q] = wgu + ((size_t)e * 2 * HH + bx * 128 + row) * DD + schunk;
  }

  const int wr = wv >> 1, wc = wv & 1;
  const int lr = lane & 15, kc = lane >> 4;

  f32x4 acc[4][4];
#pragma unroll
  for (int a = 0; a < 4; ++a)
#pragma unroll
    for (int b = 0; b < 4; ++b) acc[a][b] = f32x4{0.f, 0.f, 0.f, 0.f};

#define G1_ISSUE(b)                                                       \
  do {                                                                    \
    _Pragma("unroll")                                                     \
    for (int q = 0; q < 4; ++q) {                                         \
      gload16(pA[q], &As[b][(wv * 32 + q * 8) * 64]); pA[q] += 64;        \
      gload16(pB[q], &Bs[b][(wv * 32 + q * 8) * 64]); pB[q] += 64;        \
    }                                                                     \
  } while (0)

#define G1_COMPUTE(b)                                                     \
  do {                                                                    \
    _Pragma("unroll")                                                     \
    for (int kk = 0; kk < 2; ++kk) {                                      \
      bf16x8 af[4], bf[4];                                                \
      _Pragma("unroll")                                                   \
      for (int mf = 0; mf < 4; ++mf)                                      \
        af[mf] = *(const bf16x8*)&As[b][(wr * 64 + mf * 16 + lr) * 64 +   \
                                       ((kk * 4 + kc) ^ (lr & 7)) * 8];   \
      _Pragma("unroll")                                                   \
      for (int nf = 0; nf < 4; ++nf)                                      \
        bf[nf] = *(const bf16x8*)&Bs[b][(wc * 64 + nf * 16 + lr) * 64 +   \
                                       ((kk * 4 + kc) ^ (lr & 7)) * 8];   \
      _Pragma("unroll")                                                   \
      for (int mf = 0; mf < 4; ++mf)                                      \
        _Pragma("unroll")                                                 \
        for (int nf = 0; nf < 4; ++nf)                                    \
          acc[mf][nf] = __builtin_amdgcn_mfma_f32_16x16x32_bf16(          \
              af[mf], bf[nf], acc[mf][nf], 0, 0, 0);                      \
    }                                                                     \
  } while (0)

  G1_ISSUE(0);
  G1_ISSUE(1);
  VMCNT8(); BARX();
  for (int t = 0; t < DD / 64; ++t) {
    const int cur = t & 1;
    G1_COMPUTE(cur);
    if (t == DD / 64 - 1) break;
    BARX();
    if (t < DD / 64 - 2) { G1_ISSUE(cur); VMCNT8(); }
    else VMCNT0();
    BARX();
  }

  // epilogue: nf even = G, nf odd = U (same 16 h-cols)
#pragma unroll
  for (int mf = 0; mf < 4; ++mf)
#pragma unroll
    for (int np = 0; np < 2; ++np) {
      const f32x4 g2 = acc[mf][2 * np], u = acc[mf][2 * np + 1];
      const int hcol = bx * 64 + (wc * 2 + np) * 16 + lr;
#pragma unroll
      for (int r = 0; r < 4; ++r) {
        const int rl = m0 + wr * 64 + mf * 16 + kc * 4 + r;
        if (rl < ne) {
          const float gg = g2[r], uu = u[r];
          const float hv = gg / (1.f + __expf(-gg)) * uu;
          hbuf[(size_t)(off + rl) * HH + hcol] = f2bf(hv);
        }
      }
    }
#undef G1_ISSUE
#undef G1_COMPUTE
}

// ---- full-range decode (gemm2) ----
static __device__ __forceinline__ bool decode128(const int* counts, int tix,
                                                 int& e, int& m0, int& off, int& ne) {
  int t = tix; off = 0;
  for (e = 0; e < NE; ++e) {
    const int c = counts[e];
    const int nt = (c + 127) >> 7;
    if (t < nt) { m0 = t << 7; ne = c; return true; }
    t -= nt; off += c;
  }
  return false;
}

// ---------------- GEMM2: h(bf16) @ w3t(bf16) * prob -> atomicAdd into out ----------------
__global__ __launch_bounds__(256) void gemm2_k(
    const unsigned short* __restrict__ hbuf, const unsigned short* __restrict__ w3t,
    const int* __restrict__ counts, const int* __restrict__ perm,
    const float* __restrict__ prow, float* __restrict__ out) {
  const int bx = blockIdx.x & 7;
  int e, m0, off, ne;
  if (!decode128(counts, blockIdx.x >> 3, e, m0, off, ne)) return;
  const int n1 = bx * 128;

  __shared__ unsigned short As[2][128 * 64];
  __shared__ unsigned short Bs[2][128 * 64];

  const int tid = threadIdx.x, lane = tid & 63, wv = tid >> 6;
  const int srow = lane >> 3;
  const int schunk = ((lane & 7) ^ srow) * 8;

  const unsigned short* pA[4];
  const unsigned short* pB[4];
#pragma unroll
  for (int q = 0; q < 4; ++q) {
    const int row = wv * 32 + q * 8 + srow;
    pA[q] = hbuf + (size_t)(off + min(m0 + row, ne - 1)) * HH + schunk;
    pB[q] = w3t + ((size_t)e * DD + n1 + row) * HH + schunk;
  }

  const int wr = wv >> 1, wc = wv & 1;
  const int lr = lane & 15, kc = lane >> 4;

  f32x4 acc[4][4];
#pragma unroll
  for (int a = 0; a < 4; ++a)
#pragma unroll
    for (int b = 0; b < 4; ++b) acc[a][b] = f32x4{0.f, 0.f, 0.f, 0.f};

#define G2_ISSUE(b)                                                       \
  do {                                                                    \
    _Pragma("unroll")                                                     \
    for (int q = 0; q < 4; ++q) {                                         \
      gload16(pA[q], &As[b][(wv * 32 + q * 8) * 64]); pA[q] += 64;        \
      gload16(pB[q], &Bs[b][(wv * 32 + q * 8) * 64]); pB[q] += 64;        \
    }                                                                     \
  } while (0)

#define G2_COMPUTE(b)                                                     \
  do {                                                                    \
    _Pragma("unroll")                                                     \
    for (int kk = 0; kk < 2; ++kk) {                                      \
      bf16x8 af[4], bf[4];                                                \
      _Pragma("unroll")                                                   \
      for (int mf = 0; mf < 4; ++mf)                                      \
        af[mf] = *(const bf16x8*)&As[b][(wr * 64 + mf * 16 + lr) * 64 +   \
                                       ((kk * 4 + kc) ^ (lr & 7)) * 8];   \
      _Pragma("unroll")                                                   \
      for (int nf = 0; nf < 4; ++nf)                                      \
        bf[nf] = *(const bf16x8*)&Bs[b][(wc * 64 + nf * 16 + lr) * 64 +   \
                                       ((kk * 4 + kc) ^ (lr & 7)) * 8];   \
      _Pragma("unroll")                                                   \
      for (int mf = 0; mf < 4; ++mf)                                      \
        _Pragma("unroll")                                                 \
        for (int nf = 0; nf < 4; ++nf)                                    \
          acc[mf][nf] = __builtin_amdgcn_mfma_f32_16x16x32_bf16(          \
              af[mf], bf[nf], acc[mf][nf], 0, 0, 0);                      \
    }                                                                     \
  } while (0)

  G2_ISSUE(0);
  G2_ISSUE(1);
  VMCNT8(); BARX();
  for (int t = 0; t < HH / 64; ++t) {
    const int cur = t & 1;
    G2_COMPUTE(cur);
    if (t == HH / 64 - 1) break;
    BARX();
    if (t < HH / 64 - 2) { G2_ISSUE(cur); VMCNT8(); }
    else VMCNT0();
    BARX();
  }

  // epilogue: out[tok] += prob * acc  (fp32 atomic add, commutative -> deterministic)
#pragma unroll
  for (int mf = 0; mf < 4; ++mf)
#pragma unroll
    for (int r = 0; r < 4; ++r) {
      const int rl = m0 + wr * 64 + mf * 16 + kc * 4 + r;
      if (rl < ne) {
        const int tok = perm[off + rl];
        const float p = prow[off + rl];
        float* op = out + (size_t)tok * DD + n1 + wc * 64 + lr;
#pragma unroll
        for (int nf = 0; nf < 4; ++nf)
          atomicAdd(op + nf * 16, p * acc[mf][nf][r]);
      }
    }
#undef G2_ISSUE
#undef G2_COMPUTE
}

// ---------------- workspace layout ----------------
#define WS_COUNTS 0
#define WS_CHUNK 128
#define WS_TOPI (WS_CHUNK + 512)
#define WS_TOPP (WS_TOPI + TOK * 2 * 4)
#define WS_PERM (WS_TOPP + TOK * 2 * 4)
#define WS_PROW (WS_PERM + RTOT * 4)
#define WS_XB ((WS_PROW + RTOT * 4 + 255) & ~(size_t)255)
#define WS_H (WS_XB + (size_t)TOK * DD * 2)
#define WS_WGU (WS_H + (size_t)RTOT * HH * 2)
#define WS_W3T (WS_WGU + (size_t)NE * 2 * HH * DD * 2)
// end = WS_W3T + NE*DD*HH*2 ~= 136 MB

extern "C" void kernel_launch(void* const* d_in, const int* in_sizes, int n_in,
                              void* d_out, int out_size, void* d_ws, size_t ws_size,
                              hipStream_t stream) {
  const float* x = (const float*)d_in[0];
  const float* gw = (const float*)d_in[1];
  const float* w1 = (const float*)d_in[2];
  const float* w2 = (const float*)d_in[3];
  const float* w3 = (const float*)d_in[4];
  float* out = (float*)d_out;
  char* ws = (char*)d_ws;

  int* counts = (int*)(ws + WS_COUNTS);
  int* chunkcnt = (int*)(ws + WS_CHUNK);
  int* topi = (int*)(ws + WS_TOPI);
  float* topp = (float*)(ws + WS_TOPP);
  int* perm = (int*)(ws + WS_PERM);
  float* prow = (float*)(ws + WS_PROW);
  unsigned short* Xb = (unsigned short*)(ws + WS_XB);
  unsigned short* hbuf = (unsigned short*)(ws + WS_H);
  unsigned short* wgu = (unsigned short*)(ws + WS_WGU);
  unsigned short* w3t = (unsigned short*)(ws + WS_W3T);

  hipMemsetAsync(ws, 0, WS_CHUNK + 512, stream);
  hipMemsetAsync(out, 0, (size_t)out_size * sizeof(float), stream);
  // router (1024) + wgu transpose e0-3 (4096): period-5 interleave
  pre_k<<<5120, 256, 0, stream>>>(x, gw, Xb, topi, topp, counts, chunkcnt, w1, w2, wgu);
  // parallel compact: 128 blocks
  compact_k<<<NE * 16, 256, 0, stream>>>(topi, topp, counts, chunkcnt, perm, prow);
  // gemm1a: tiles e0-3 (68*32 slots) + wgu transpose e4-7 (4096), period 3
  gemm1_k<<<HALFSLOTS * 32 * 3, 256, 0, stream>>>(
      Xb, wgu, counts, perm, hbuf, w1, w2, w3, wgu, w3t, 0, 0);
  // gemm1b: tiles e4-7 + w3t transpose all (4096), period 3
  gemm1_k<<<HALFSLOTS * 32 * 3, 256, 0, stream>>>(
      Xb, wgu, counts, perm, hbuf, w1, w2, w3, wgu, w3t, 4, 1);
  gemm2_k<<<MAXT1 * 8, 256, 0, stream>>>(hbuf, w3t, counts, perm, prow, out);
}

// Round 23
// 255.003 us; speedup vs baseline: 1.3216x; 1.3216x over previous
//
#include <hip/hip_runtime.h>
#include <hip/hip_bf16.h>

// B=2,S=2048 -> T=4096 tokens, D=1024, H=2048, E=8, top_k=2
#define TOK 4096
#define DD 1024
#define HH 2048
#define NE 8
#define RTOT (TOK * 2)
#define MAXT1 72
#define G1TILES (MAXT1 * 32)   // 2304 gemm1 tiles

typedef __attribute__((ext_vector_type(8))) short bf16x8;
typedef __attribute__((ext_vector_type(4))) float f32x4;

static __device__ __forceinline__ unsigned short f2bf(float f) {
  union { float f; unsigned int u; } v; v.f = f;
  unsigned int r = v.u + 0x7fffu + ((v.u >> 16) & 1u);
  return (unsigned short)(r >> 16);
}

// async global->LDS, 16B/lane; LDS dest = wave-uniform base + lane*16
static __device__ __forceinline__ void gload16(const unsigned short* g, unsigned short* l) {
  __builtin_amdgcn_global_load_lds(
      (const __attribute__((address_space(1))) unsigned int*)g,
      (__attribute__((address_space(3))) unsigned int*)l, 16, 0, 0);
}

// packed f32x2 -> bf16x2 (RNE), single HW instruction
#define CVT(d, lo, hi) asm("v_cvt_pk_bf16_f32 %0, %1, %2" : "=v"(d) : "v"(lo), "v"(hi))

#define BARX() do { asm volatile("" ::: "memory"); __builtin_amdgcn_s_barrier(); asm volatile("" ::: "memory"); } while (0)
#define VMCNT8() asm volatile("s_waitcnt vmcnt(8)" ::: "memory")
#define VMCNT0() asm volatile("s_waitcnt vmcnt(0)" ::: "memory")

// expert count from 16 chunk counters (512B, L2-hot)
static __device__ __forceinline__ int ecount(const int* chunkcnt, int e) {
  int s = 0;
#pragma unroll
  for (int i = 0; i < 16; ++i) s += chunkcnt[e * 16 + i];
  return s;
}

// ---------------- pre-kernel: router + w1/w2 transpose, INTERLEAVED ----------------
// bid%9==0 -> router block (1024 of 9216); else transpose (8192).
// R23: counts[] atomics REMOVED (8192 adds over 8 addrs serialized ~1024-deep at L2);
// only chunkcnt atomics remain (128 addrs, 64 hits each).
__global__ __launch_bounds__(256) void pre_k(
    const float* __restrict__ x, const float* __restrict__ gw,
    unsigned short* __restrict__ xb, int* __restrict__ topi, float* __restrict__ topp,
    int* __restrict__ chunkcnt,
    const float* __restrict__ w1, const float* __restrict__ w2,
    unsigned short* __restrict__ wgu) {
  __shared__ unsigned short tbuf[64 * 72];
  const int tid = threadIdx.x;
  const int lane = tid & 63, wv = tid >> 6;
  const int rb9 = blockIdx.x / 9;

  if (blockIdx.x - rb9 * 9 == 0) {
    // ---- router ----
    const int t = rb9 * 4 + wv;
    const float4* xr = (const float4*)(x + (size_t)t * DD);
    unsigned int* xw = (unsigned int*)(xb + (size_t)t * DD);
    float acc[NE];
#pragma unroll
    for (int e = 0; e < NE; ++e) acc[e] = 0.f;
#pragma unroll
    for (int i = 0; i < 4; ++i) {
      const float4 xv = xr[i * 64 + lane];
      unsigned int p0, p1;
      CVT(p0, xv.x, xv.y);
      CVT(p1, xv.z, xv.w);
      xw[(i * 64 + lane) * 2] = p0;
      xw[(i * 64 + lane) * 2 + 1] = p1;
#pragma unroll
      for (int e = 0; e < NE; ++e) {
        const float4 gv = ((const float4*)(gw + (size_t)e * DD))[i * 64 + lane];
        acc[e] += xv.x * gv.x + xv.y * gv.y + xv.z * gv.z + xv.w * gv.w;
      }
    }
#pragma unroll
    for (int e = 0; e < NE; ++e)
#pragma unroll
      for (int s = 32; s > 0; s >>= 1) acc[e] += __shfl_xor(acc[e], s, 64);
    if (lane == 0) {
      int i0 = 0; float v0 = acc[0];
#pragma unroll
      for (int e = 1; e < NE; ++e) if (acc[e] > v0) { v0 = acc[e]; i0 = e; }
      int i1 = -1; float v1 = -1e30f;
#pragma unroll
      for (int e = 0; e < NE; ++e) if (e != i0 && acc[e] > v1) { v1 = acc[e]; i1 = e; }
      const float ex = __expf(v1 - v0);
      const float inv = 1.f / (1.f + ex);
      topi[t * 2] = i0; topi[t * 2 + 1] = i1;
      topp[t * 2] = inv; topp[t * 2 + 1] = ex * inv;
      const int c = t >> 8;                    // 256-token chunk
      atomicAdd(&chunkcnt[i0 * 16 + c], 1);
      atomicAdd(&chunkcnt[i1 * 16 + c], 1);
    }
    return;
  }

  // ---- w1/w2 transpose: 64x64 tile -> wgu interleaved G/U rows ----
  const int bid = blockIdx.x - rb9 - 1;    // 0..8191
  const int z = bid >> 9;                  // 0..15
  const int xt = bid & 511;
  const int mat = z >> 3, e = z & 7;
  const float* in = (mat ? w2 : w1) + (size_t)e * DD * HH;
  const int tc = xt & 31, tr = xt >> 5;
  const int c0 = tc * 64, r0 = tr * 64;
#pragma unroll
  for (int p = 0; p < 4; ++p) {
    const int rb = (wv * 4 + p) * 4;
    ushort4 o;
    o.x = f2bf(in[(size_t)(r0 + rb + 0) * HH + c0 + lane]);
    o.y = f2bf(in[(size_t)(r0 + rb + 1) * HH + c0 + lane]);
    o.z = f2bf(in[(size_t)(r0 + rb + 2) * HH + c0 + lane]);
    o.w = f2bf(in[(size_t)(r0 + rb + 3) * HH + c0 + lane]);
    *(ushort4*)&tbuf[lane * 72 + rb] = o;
  }
  __syncthreads();
#pragma unroll
  for (int q = 0; q < 2; ++q) {
    const int idx = q * 256 + tid;
    const int crow = idx >> 3, seg = idx & 7;
    const int j = c0 + crow;
    const int R = ((j >> 4) << 5) + (j & 15) + mat * 16;
    *(uint4*)&wgu[((size_t)e * 2 * HH + R) * DD + r0 + seg * 8] =
        *(const uint4*)&tbuf[crow * 72 + seg * 8];
  }
}

// ---------------- parallel compact: 128 blocks = (e, 256-token chunk) ----------------
// base = prefix over experts (chunkcnt sums) + prefix over chunks within e.
__global__ __launch_bounds__(256) void compact_k(
    const int* __restrict__ topi, const float* __restrict__ topp,
    const int* __restrict__ chunkcnt, int* __restrict__ perm, float* __restrict__ prow) {
  const int e = blockIdx.x >> 4, c = blockIdx.x & 15;
  const int tid = threadIdx.x, lane = tid & 63, wv = tid >> 6;
  __shared__ int wsum[4];
  __shared__ int base_s;
  if (tid == 0) {
    int b = 0;
    for (int i = 0; i < e * 16 + c; ++i) b += chunkcnt[(i < e * 16) ? i : i];
    // simpler exact form:
    b = 0;
    for (int i = 0; i < e; ++i) b += ecount(chunkcnt, i);
    for (int i = 0; i < c; ++i) b += chunkcnt[e * 16 + i];
    base_s = b;
  }
  const int t = c * 256 + tid;
  const int a = topi[2 * t], bq = topi[2 * t + 1];
  const int k = (a == e) ? 0 : ((bq == e) ? 1 : -1);
  const unsigned long long bal = __ballot(k >= 0);
  const int rank = __popcll(bal & ((1ull << lane) - 1ull));
  if (lane == 0) wsum[wv] = __popcll(bal);
  __syncthreads();
  int woff = 0;
#pragma unroll
  for (int i = 0; i < 4; ++i) if (i < wv) woff += wsum[i];
  if (k >= 0) {
    const int pos = base_s + woff + rank;
    perm[pos] = t;
    prow[pos] = topp[2 * t + k];
  }
}

// ---- inline tile decode (BM=128) from chunkcnt: tix -> (e, m0, off, ne) ----
static __device__ __forceinline__ bool decode128(const int* chunkcnt, int tix,
                                                 int& e, int& m0, int& off, int& ne) {
  int t = tix; off = 0;
  for (e = 0; e < NE; ++e) {
    const int c = ecount(chunkcnt, e);
    const int nt = (c + 127) >> 7;
    if (t < nt) { m0 = t << 7; ne = c; return true; }
    t -= nt; off += c;
  }
  return false;
}

// ---------------- GEMM1 with INTERLEAVED w3-transpose blocks ----------------
// 6400 blocks, period-25: rem<9 -> gemm tile (2304), rem>=9 -> w3-transpose (4096).
__global__ __launch_bounds__(256) void gemm1_k(
    const unsigned short* __restrict__ Xb, const unsigned short* __restrict__ wgu,
    const int* __restrict__ chunkcnt, const int* __restrict__ perm,
    unsigned short* __restrict__ hbuf,
    const float* __restrict__ w3, unsigned short* __restrict__ w3t) {
  __shared__ unsigned short As[2][128 * 64];
  __shared__ unsigned short Bs[2][128 * 64];

  const int tid = threadIdx.x, lane = tid & 63, wv = tid >> 6;
  const int grp = blockIdx.x / 25, rem = blockIdx.x % 25;

  if (rem >= 9) {
    // ---- w3 transpose ----
    unsigned short* tbuf = &As[0][0];
    const int bid = grp * 16 + (rem - 9);    // 0..4095
    const int e = bid >> 9, xt = bid & 511;
    const int tc = xt & 15, tr = xt >> 4;
    const int c0 = tc * 64, r0 = tr * 64;
    const float* in = w3 + (size_t)e * HH * DD;
#pragma unroll
    for (int p = 0; p < 4; ++p) {
      const int rb = (wv * 4 + p) * 4;
      ushort4 o;
      o.x = f2bf(in[(size_t)(r0 + rb + 0) * DD + c0 + lane]);
      o.y = f2bf(in[(size_t)(r0 + rb + 1) * DD + c0 + lane]);
      o.z = f2bf(in[(size_t)(r0 + rb + 2) * DD + c0 + lane]);
      o.w = f2bf(in[(size_t)(r0 + rb + 3) * DD + c0 + lane]);
      *(ushort4*)&tbuf[lane * 72 + rb] = o;
    }
    __syncthreads();
#pragma unroll
    for (int q = 0; q < 2; ++q) {
      const int idx = q * 256 + tid;
      const int crow = idx >> 3, seg = idx & 7;
      *(uint4*)&w3t[((size_t)e * DD + c0 + crow) * HH + r0 + seg * 8] =
          *(const uint4*)&tbuf[crow * 72 + seg * 8];
    }
    return;
  }

  const int g = grp * 9 + rem;             // gemm tile 0..2303
  const int bx = g & 31;
  int e, m0, off, ne;
  if (!decode128(chunkcnt, g >> 5, e, m0, off, ne)) return;

  const int srow = lane >> 3;
  const int schunk = ((lane & 7) ^ srow) * 8;

  const unsigned short* pA[4];
  const unsigned short* pB[4];
#pragma unroll
  for (int q = 0; q < 4; ++q) {
    const int row = wv * 32 + q * 8 + srow;
    pA[q] = Xb + (size_t)perm[off + min(m0 + row, ne - 1)] * DD + schunk;
    pB[q] = wgu + ((size_t)e * 2 * HH + bx * 128 + row) * DD + schunk;
  }

  const int wr = wv >> 1, wc = wv & 1;
  const int lr = lane & 15, kc = lane >> 4;

  f32x4 acc[4][4];
#pragma unroll
  for (int a = 0; a < 4; ++a)
#pragma unroll
    for (int b = 0; b < 4; ++b) acc[a][b] = f32x4{0.f, 0.f, 0.f, 0.f};

#define G1_ISSUE(b)                                                       \
  do {                                                                    \
    _Pragma("unroll")                                                     \
    for (int q = 0; q < 4; ++q) {                                         \
      gload16(pA[q], &As[b][(wv * 32 + q * 8) * 64]); pA[q] += 64;        \
      gload16(pB[q], &Bs[b][(wv * 32 + q * 8) * 64]); pB[q] += 64;        \
    }                                                                     \
  } while (0)

#define G1_COMPUTE(b)                                                     \
  do {                                                                    \
    _Pragma("unroll")                                                     \
    for (int kk = 0; kk < 2; ++kk) {                                      \
      bf16x8 af[4], bf[4];                                                \
      _Pragma("unroll")                                                   \
      for (int mf = 0; mf < 4; ++mf)                                      \
        af[mf] = *(const bf16x8*)&As[b][(wr * 64 + mf * 16 + lr) * 64 +   \
                                       ((kk * 4 + kc) ^ (lr & 7)) * 8];   \
      _Pragma("unroll")                                                   \
      for (int nf = 0; nf < 4; ++nf)                                      \
        bf[nf] = *(const bf16x8*)&Bs[b][(wc * 64 + nf * 16 + lr) * 64 +   \
                                       ((kk * 4 + kc) ^ (lr & 7)) * 8];   \
      _Pragma("unroll")                                                   \
      for (int mf = 0; mf < 4; ++mf)                                      \
        _Pragma("unroll")                                                 \
        for (int nf = 0; nf < 4; ++nf)                                    \
          acc[mf][nf] = __builtin_amdgcn_mfma_f32_16x16x32_bf16(          \
              af[mf], bf[nf], acc[mf][nf], 0, 0, 0);                      \
    }                                                                     \
  } while (0)

  G1_ISSUE(0);
  G1_ISSUE(1);
  VMCNT8(); BARX();
  for (int t = 0; t < DD / 64; ++t) {
    const int cur = t & 1;
    G1_COMPUTE(cur);
    if (t == DD / 64 - 1) break;
    BARX();
    if (t < DD / 64 - 2) { G1_ISSUE(cur); VMCNT8(); }
    else VMCNT0();
    BARX();
  }

  // epilogue: nf even = G, nf odd = U (same 16 h-cols)
#pragma unroll
  for (int mf = 0; mf < 4; ++mf)
#pragma unroll
    for (int np = 0; np < 2; ++np) {
      const f32x4 g2 = acc[mf][2 * np], u = acc[mf][2 * np + 1];
      const int hcol = bx * 64 + (wc * 2 + np) * 16 + lr;
#pragma unroll
      for (int r = 0; r < 4; ++r) {
        const int rl = m0 + wr * 64 + mf * 16 + kc * 4 + r;
        if (rl < ne) {
          const float gg = g2[r], uu = u[r];
          const float hv = gg / (1.f + __expf(-gg)) * uu;
          hbuf[(size_t)(off + rl) * HH + hcol] = f2bf(hv);
        }
      }
    }
#undef G1_ISSUE
#undef G1_COMPUTE
}

// ---------------- GEMM2: h(bf16) @ w3t(bf16) * prob -> atomicAdd into out ----------------
__global__ __launch_bounds__(256) void gemm2_k(
    const unsigned short* __restrict__ hbuf, const unsigned short* __restrict__ w3t,
    const int* __restrict__ chunkcnt, const int* __restrict__ perm,
    const float* __restrict__ prow, float* __restrict__ out) {
  const int bx = blockIdx.x & 7;
  int e, m0, off, ne;
  if (!decode128(chunkcnt, blockIdx.x >> 3, e, m0, off, ne)) return;
  const int n1 = bx * 128;

  __shared__ unsigned short As[2][128 * 64];
  __shared__ unsigned short Bs[2][128 * 64];

  const int tid = threadIdx.x, lane = tid & 63, wv = tid >> 6;
  const int srow = lane >> 3;
  const int schunk = ((lane & 7) ^ srow) * 8;

  const unsigned short* pA[4];
  const unsigned short* pB[4];
#pragma unroll
  for (int q = 0; q < 4; ++q) {
    const int row = wv * 32 + q * 8 + srow;
    pA[q] = hbuf + (size_t)(off + min(m0 + row, ne - 1)) * HH + schunk;
    pB[q] = w3t + ((size_t)e * DD + n1 + row) * HH + schunk;
  }

  const int wr = wv >> 1, wc = wv & 1;
  const int lr = lane & 15, kc = lane >> 4;

  f32x4 acc[4][4];
#pragma unroll
  for (int a = 0; a < 4; ++a)
#pragma unroll
    for (int b = 0; b < 4; ++b) acc[a][b] = f32x4{0.f, 0.f, 0.f, 0.f};

#define G2_ISSUE(b)                                                       \
  do {                                                                    \
    _Pragma("unroll")                                                     \
    for (int q = 0; q < 4; ++q) {                                         \
      gload16(pA[q], &As[b][(wv * 32 + q * 8) * 64]); pA[q] += 64;        \
      gload16(pB[q], &Bs[b][(wv * 32 + q * 8) * 64]); pB[q] += 64;        \
    }                                                                     \
  } while (0)

#define G2_COMPUTE(b)                                                     \
  do {                                                                    \
    _Pragma("unroll")                                                     \
    for (int kk = 0; kk < 2; ++kk) {                                      \
      bf16x8 af[4], bf[4];                                                \
      _Pragma("unroll")                                                   \
      for (int mf = 0; mf < 4; ++mf)                                      \
        af[mf] = *(const bf16x8*)&As[b][(wr * 64 + mf * 16 + lr) * 64 +   \
                                       ((kk * 4 + kc) ^ (lr & 7)) * 8];   \
      _Pragma("unroll")                                                   \
      for (int nf = 0; nf < 4; ++nf)                                      \
        bf[nf] = *(const bf16x8*)&Bs[b][(wc * 64 + nf * 16 + lr) * 64 +   \
                                       ((kk * 4 + kc) ^ (lr & 7)) * 8];   \
      _Pragma("unroll")                                                   \
      for (int mf = 0; mf < 4; ++mf)                                      \
        _Pragma("unroll")                                                 \
        for (int nf = 0; nf < 4; ++nf)                                    \
          acc[mf][nf] = __builtin_amdgcn_mfma_f32_16x16x32_bf16(          \
              af[mf], bf[nf], acc[mf][nf], 0, 0, 0);                      \
    }                                                                     \
  } while (0)

  G2_ISSUE(0);
  G2_ISSUE(1);
  VMCNT8(); BARX();
  for (int t = 0; t < HH / 64; ++t) {
    const int cur = t & 1;
    G2_COMPUTE(cur);
    if (t == HH / 64 - 1) break;
    BARX();
    if (t < HH / 64 - 2) { G2_ISSUE(cur); VMCNT8(); }
    else VMCNT0();
    BARX();
  }

  // epilogue: out[tok] += prob * acc  (fp32 atomic add, commutative -> deterministic)
#pragma unroll
  for (int mf = 0; mf < 4; ++mf)
#pragma unroll
    for (int r = 0; r < 4; ++r) {
      const int rl = m0 + wr * 64 + mf * 16 + kc * 4 + r;
      if (rl < ne) {
        const int tok = perm[off + rl];
        const float p = prow[off + rl];
        float* op = out + (size_t)tok * DD + n1 + wc * 64 + lr;
#pragma unroll
        for (int nf = 0; nf < 4; ++nf)
          atomicAdd(op + nf * 16, p * acc[mf][nf][r]);
      }
    }
#undef G2_ISSUE
#undef G2_COMPUTE
}

// ---------------- workspace layout ----------------
#define WS_CHUNK 0                            // 8*16 ints = 512B
#define WS_TOPI (WS_CHUNK + 512)
#define WS_TOPP (WS_TOPI + TOK * 2 * 4)
#define WS_PERM (WS_TOPP + TOK * 2 * 4)
#define WS_PROW (WS_PERM + RTOT * 4)
#define WS_XB ((WS_PROW + RTOT * 4 + 255) & ~(size_t)255)
#define WS_H (WS_XB + (size_t)TOK * DD * 2)
#define WS_WGU (WS_H + (size_t)RTOT * HH * 2)
#define WS_W3T (WS_WGU + (size_t)NE * 2 * HH * DD * 2)
// end = WS_W3T + NE*DD*HH*2 ~= 136 MB

extern "C" void kernel_launch(void* const* d_in, const int* in_sizes, int n_in,
                              void* d_out, int out_size, void* d_ws, size_t ws_size,
                              hipStream_t stream) {
  const float* x = (const float*)d_in[0];
  const float* gw = (const float*)d_in[1];
  const float* w1 = (const float*)d_in[2];
  const float* w2 = (const float*)d_in[3];
  const float* w3 = (const float*)d_in[4];
  float* out = (float*)d_out;
  char* ws = (char*)d_ws;

  int* chunkcnt = (int*)(ws + WS_CHUNK);
  int* topi = (int*)(ws + WS_TOPI);
  float* topp = (float*)(ws + WS_TOPP);
  int* perm = (int*)(ws + WS_PERM);
  float* prow = (float*)(ws + WS_PROW);
  unsigned short* Xb = (unsigned short*)(ws + WS_XB);
  unsigned short* hbuf = (unsigned short*)(ws + WS_H);
  unsigned short* wgu = (unsigned short*)(ws + WS_WGU);
  unsigned short* w3t = (unsigned short*)(ws + WS_W3T);

  hipMemsetAsync(ws, 0, 512, stream);
  hipMemsetAsync(out, 0, (size_t)out_size * sizeof(float), stream);
  // router (1024) interleaved with w1/w2 transpose (8192): 9216 blocks
  pre_k<<<9216, 256, 0, stream>>>(x, gw, Xb, topi, topp, chunkcnt, w1, w2, wgu);
  // parallel compact: 128 blocks (e, chunk)
  compact_k<<<NE * 16, 256, 0, stream>>>(topi, topp, chunkcnt, perm, prow);
  // gemm1 tiles (2304) interleaved with w3-transpose (4096): 6400 blocks
  gemm1_k<<<6400, 256, 0, stream>>>(Xb, wgu, chunkcnt, perm, hbuf, w3, w3t);
  gemm2_k<<<MAXT1 * 8, 256, 0, stream>>>(hbuf, w3t, chunkcnt, perm, prow, out);
}